// Round 11
// baseline (819.364 us; speedup 1.0000x reference)
//
#include <hip/hip_runtime.h>

#define N_USERS    50000
#define N_ENTITIES 100000
#define EMB        64
#define N_EDGES    2000000
#define NNZ        2000000
#define SLOPE      0.2f

// ---- bucket geometry (r6-verified) -----------------------------------------
#define KROWS   256                 // entity rows per kg bucket
#define KSHIFT  8
#define NBK     391                 // ceil(100000/256)
#define UROWS   128                 // user rows per bucket
#define USHIFT  7
#define NBU     391                 // ceil(50000/128)
#define KCAP    5632                // static region: mean 5115 + 7.2 sigma
#define UCAP    5632
#define CHK     8192                // edges per partition chunk
#define NCH_K   ((N_EDGES + CHK - 1) / CHK)          // 245
#define NCH_U   ((NNZ + CHK - 1) / CHK)              // 245
#define NCHT    (NCH_K + NCH_U + 1)                  // 491 (+1 small_dense)
#define NQ      (NBK + NBU)         // 782 acc buckets
#define ACCBLK  512                 // persistent blocks (2/CU thread-cap)
// counters: ctrs[0]=taskCtr(phase A)  ctrs[1]=chunksDone  ctrs[2]=accCtr
#define SMEM_LL 5825                // 46.6 KB union (user bucket worst case)

// ============================================================================
// Small dense math on caller-provided LDS scratch (2304 floats).
// All threads of the calling block must enter (barriers by everyone).
// ============================================================================
__device__ void small_dense_body(int l, float* __restrict__ sh,
                                 const float* __restrict__ latent_emb,
                                 const float* __restrict__ weight,
                                 const float* __restrict__ W_weight_att,
                                 const float* __restrict__ b_weight_att,
                                 const float* __restrict__ W1,
                                 const float* __restrict__ b1,
                                 const float* __restrict__ W2,
                                 const float* __restrict__ b2,
                                 float* __restrict__ P_out,
                                 float* __restrict__ c_out,
                                 float* __restrict__ latent_new_out) {
    float* lat1 = sh;            // 512
    float* lat2 = sh + 512;      // 512
    float* wl2  = sh + 1024;     // 1024
    float* srp  = sh + 2048;     // 128
    float* soft = sh + 2176;     // 128

    if (l < 64) {
        for (int f = 0; f < 8; ++f) {
            float a1 = b1[l], a2 = b2[l];
            for (int k = 0; k < 64; ++k) {
                float le = latent_emb[f * 64 + k];
                a1 += le * W1[l * 64 + k];
                a2 += le * W2[l * 64 + k];
            }
            lat1[f * 64 + l] = a1;
            lat2[f * 64 + l] = a2;
        }
        for (int r = 0; r < 16; ++r) {
            float a = b2[l];
            for (int k = 0; k < 64; ++k) a += weight[r * 64 + k] * W2[l * 64 + k];
            wl2[r * 64 + l] = a;
        }
    }
    __syncthreads();

    if (l < 64) {
        for (int f = 0; f < 8; ++f) {
            float p = 0.f;
            for (int d = 0; d < 64; ++d) p += W1[d * 64 + l] * lat1[f * 64 + d];
            P_out[l * 8 + f] = p;
        }
        if (l < 8) {
            float cc = 0.f;
            for (int d = 0; d < 64; ++d) cc += b1[d] * lat1[l * 64 + d];
            c_out[l] = cc;
        }
        for (int idx = l; idx < 128; idx += 64) {
            int f = idx >> 4, r = idx & 15;
            float a = 0.f;
            for (int d = 0; d < 64; ++d) a += lat2[f * 64 + d] * wl2[r * 64 + d];
            srp[idx] = a;
        }
    }
    __syncthreads();

    if (l < 8) {
        int f = l;
        float att[16];
        float mx = -1e30f;
        for (int k = 0; k < 16; ++k) {
            float a = b_weight_att[k];
            for (int j = 0; j < 16; ++j) a += srp[f * 16 + j] * W_weight_att[k * 16 + j];
            a = a > 0.f ? a : SLOPE * a;
            att[k] = a;
            mx = fmaxf(mx, a);
        }
        float s = 0.f;
        for (int k = 0; k < 16; ++k) { att[k] = expf(att[k] - mx); s += att[k]; }
        float inv = 1.f / s;
        for (int k = 0; k < 16; ++k) soft[f * 16 + k] = att[k] * inv;
    }
    __syncthreads();

    if (l < 64) {
        for (int f = 0; f < 8; ++f) {
            float a = 0.f;
            for (int r = 0; r < 16; ++r) a += soft[f * 16 + r] * weight[r * 64 + l];
            latent_new_out[f * 64 + l] = a;
        }
    }
}

__global__ void small_dense(const float* __restrict__ latent_emb,
                            const float* __restrict__ weight,
                            const float* __restrict__ W_weight_att,
                            const float* __restrict__ b_weight_att,
                            const float* __restrict__ W1,
                            const float* __restrict__ b1,
                            const float* __restrict__ W2,
                            const float* __restrict__ b2,
                            float* __restrict__ P_out,
                            float* __restrict__ c_out,
                            float* __restrict__ latent_new_out) {
    __shared__ float sh[2304];
    small_dense_body(threadIdx.x, sh, latent_emb, weight, W_weight_att,
                     b_weight_att, W1, b1, W2, b2, P_out, c_out, latent_new_out);
}

// ============================================================================
// FUSED persistent kernel: phase A (partition, task-stolen chunks, direct
// placement into static per-bucket regions) -> release/acquire transition
// (deadlock-free: spin waits on TASKS, not blocks) -> phase B (r6-verified
// bucket accumulate, work-stolen).
// kg payload: tail(0..16)|type-1(17..20)|rowlow(21..28); user: int2{col|rowlow<<17, val}
// ============================================================================
__global__ __launch_bounds__(1024, 8) void fused_all(
        const int* __restrict__ head, const int* __restrict__ tail,
        const int* __restrict__ etype,
        const int* __restrict__ urows, const int* __restrict__ ucols,
        const float* __restrict__ uvals,
        int* __restrict__ ctrs, int* __restrict__ kgCur, int* __restrict__ uCur,
        int* __restrict__ kgPay, int2* __restrict__ uPay,
        const float* __restrict__ latent_emb,
        const float* __restrict__ weight,
        const float* __restrict__ W_weight_att,
        const float* __restrict__ b_weight_att,
        const float* __restrict__ W1, const float* __restrict__ b1,
        const float* __restrict__ W2, const float* __restrict__ b2,
        const float* __restrict__ entity_emb,
        const float* __restrict__ user_emb,
        const float* __restrict__ W_user_att,
        const float* __restrict__ b_user_att,
        float* __restrict__ Pbuf, float* __restrict__ cbuf,
        float* __restrict__ lat_out,
        float* __restrict__ ent_out, float* __restrict__ user_out) {
    __shared__ long long smem8[SMEM_LL];    // 46.6 KB union
    __shared__ int sidx;
    int t = threadIdx.x;

    // ---------------- phase A: partition ----------------
    for (;;) {
        __syncthreads();
        if (t == 0) sidx = atomicAdd(&ctrs[0], 1);
        __syncthreads();
        int cid = sidx;
        if (cid >= NCHT) break;

        if (cid == NCHT - 1) {
            small_dense_body(t, (float*)smem8, latent_emb, weight, W_weight_att,
                             b_weight_att, W1, b1, W2, b2, Pbuf, cbuf, lat_out);
        } else if (cid < NCH_K) {
            // ---- kg chunk: LDS hist -> batched reserve -> direct place ----
            int* lh = (int*)smem8;           // 391
            int* lb = lh + NBK;              // 391
            int base = cid * CHK;
            for (int x = t; x < NBK; x += 1024) lh[x] = 0;
            __syncthreads();
            int kreg[CHK / 1024];            // 8 staged keys
#pragma unroll
            for (int j = 0; j < CHK / 1024; ++j) {
                int i = base + j * 1024 + t;
                int h = (i < N_EDGES) ? head[i] : -1;
                kreg[j] = h;
                if (h >= 0) atomicAdd(&lh[h >> KSHIFT], 1);
            }
            __syncthreads();
            for (int x = t; x < NBK; x += 1024) {
                int c = lh[x];
                lb[x] = c ? atomicAdd(&kgCur[x], c) : 0;
                lh[x] = 0;
            }
            __syncthreads();
#pragma unroll
            for (int j = 0; j < CHK / 1024; ++j) {
                int h = kreg[j];
                if (h >= 0) {
                    int i = base + j * 1024 + t;
                    int b = h >> KSHIFT;
                    int o = lb[b] + atomicAdd(&lh[b], 1);
                    if (o < KCAP)            // overflow-dropped (P~1e-10)
                        kgPay[b * KCAP + o] =
                            tail[i] | ((etype[i] - 1) << 17) | ((h & (KROWS - 1)) << 21);
                }
            }
        } else {
            // ---- user chunk ----
            int* lh = (int*)smem8;
            int* lb = lh + NBU;
            int base = (cid - NCH_K) * CHK;
            for (int x = t; x < NBU; x += 1024) lh[x] = 0;
            __syncthreads();
            int kreg[CHK / 1024];
#pragma unroll
            for (int j = 0; j < CHK / 1024; ++j) {
                int i = base + j * 1024 + t;
                int r = (i < NNZ) ? urows[i] : -1;
                kreg[j] = r;
                if (r >= 0) atomicAdd(&lh[r >> USHIFT], 1);
            }
            __syncthreads();
            for (int x = t; x < NBU; x += 1024) {
                int c = lh[x];
                lb[x] = c ? atomicAdd(&uCur[x], c) : 0;
                lh[x] = 0;
            }
            __syncthreads();
#pragma unroll
            for (int j = 0; j < CHK / 1024; ++j) {
                int r = kreg[j];
                if (r >= 0) {
                    int i = base + j * 1024 + t;
                    int b = r >> USHIFT;
                    int o = lb[b] + atomicAdd(&lh[b], 1);
                    if (o < UCAP)
                        uPay[b * UCAP + o] =
                            make_int2(ucols[i] | ((r & (UROWS - 1)) << 17),
                                      __float_as_int(uvals[i]));
                }
            }
        }
        __threadfence();                     // make this chunk's stores agent-visible
        __syncthreads();
        if (t == 0)
            __hip_atomic_fetch_add(&ctrs[1], 1, __ATOMIC_RELEASE,
                                   __HIP_MEMORY_SCOPE_AGENT);
    }

    // ---------------- transition: wait for all partition tasks ----------------
    if (t == 0) {
        while (__hip_atomic_load(&ctrs[1], __ATOMIC_ACQUIRE,
                                 __HIP_MEMORY_SCOPE_AGENT) < NCHT)
            __builtin_amdgcn_s_sleep(2);
    }
    __syncthreads();

    // ---------------- phase B: accumulate (r6-verified body) ----------------
    int d = t & 63, wv = t >> 6;             // wv 0..15

    for (;;) {
        __syncthreads();                     // previous bucket's LDS reads done
        if (t == 0) sidx = atomicAdd(&ctrs[2], 1);
        __syncthreads();
        int q = sidx;
        if (q >= NQ) return;                 // uniform exit

        if (q < NBU) {
            // ---------------- USER bucket ----------------
            int2* spay = (int2*)smem8;               // UCAP int2
            int* lcnt = (int*)(spay + UCAP);         // 128
            int* lofs = lcnt + UROWS;                // 129
            int* sc   = lofs + UROWS + 1;            // 128
            int bk = q;
            int start = bk * UCAP;
            int n = __hip_atomic_load(&uCur[bk], __ATOMIC_RELAXED,
                                      __HIP_MEMORY_SCOPE_AGENT);
            if (n > UCAP) n = UCAP;

            if (t < UROWS) lcnt[t] = 0;
            __syncthreads();
            for (int i = t; i < n; i += 1024)
                atomicAdd(&lcnt[(uPay[start + i].x >> 17) & (UROWS - 1)], 1);
            __syncthreads();
            if (t < UROWS) sc[t] = lcnt[t];
            __syncthreads();
            for (int off = 1; off < UROWS; off <<= 1) {
                int v = (t < UROWS && t >= off) ? sc[t - off] : 0;
                __syncthreads();
                if (t < UROWS) sc[t] += v;
                __syncthreads();
            }
            if (t < UROWS) { int e = sc[t] - lcnt[t]; lofs[t] = e; lcnt[t] = e; }
            if (t == 0) lofs[UROWS] = n;
            __syncthreads();
            for (int i = t; i < n; i += 1024) {
                int2 v = uPay[start + i];
                int p = atomicAdd(&lcnt[(v.x >> 17) & (UROWS - 1)], 1);
                spay[p] = v;
            }
            __syncthreads();

            int rowbase = bk * UROWS;
            for (int rr = 0; rr < UROWS / 16; ++rr) {
                int r = wv * (UROWS / 16) + rr;
                int gr = rowbase + r;
                if (gr >= N_USERS) break;            // wave-uniform; last bucket only
                int s0 = lofs[r], e0 = lofs[r + 1];
                float acc = 0.f;
                int i = s0;
                for (; i + 7 < e0; i += 8) {
                    float a0 = 0.f, a1 = 0.f;
#pragma unroll
                    for (int u = 0; u < 8; u += 2) {
                        int2 va = spay[i + u], vb = spay[i + u + 1];
                        a0 += __int_as_float(va.y) * entity_emb[(va.x & 0x1FFFF) * EMB + d];
                        a1 += __int_as_float(vb.y) * entity_emb[(vb.x & 0x1FFFF) * EMB + d];
                    }
                    acc += a0 + a1;
                }
                for (; i < e0; ++i) {
                    int2 v = spay[i];
                    acc += __int_as_float(v.y) * entity_emb[(v.x & 0x1FFFF) * EMB + d];
                }

                // fused attention gating epilogue for this row
                float ue = user_emb[gr * EMB + d];
                float s[8];
#pragma unroll
                for (int f = 0; f < 8; ++f) s[f] = ue * Pbuf[d * 8 + f];
#pragma unroll
                for (int off = 32; off; off >>= 1) {
#pragma unroll
                    for (int f = 0; f < 8; ++f) s[f] += __shfl_xor(s[f], off, 64);
                }
#pragma unroll
                for (int f = 0; f < 8; ++f) s[f] += cbuf[f];
                float att[8];
                float mx = -1e30f;
#pragma unroll
                for (int k = 0; k < 8; ++k) {
                    float a = b_user_att[k];
#pragma unroll
                    for (int j = 0; j < 8; ++j) a += s[j] * W_user_att[k * 8 + j];
                    a = a > 0.f ? a : SLOPE * a;
                    att[k] = a;
                    mx = fmaxf(mx, a);
                }
                float sum = 0.f;
#pragma unroll
                for (int k = 0; k < 8; ++k) { att[k] = __expf(att[k] - mx); sum += att[k]; }
                float inv = 1.f / sum;
                float g = 0.f;
#pragma unroll
                for (int f = 0; f < 8; ++f) g += att[f] * inv * lat_out[f * EMB + d];
                user_out[gr * EMB + d] = acc * (1.f + g);
            }
        } else {
            // ---------------- KG bucket ----------------
            int* spay = (int*)smem8;                 // KCAP ints
            int* lcnt = spay + KCAP;                 // 256
            int* lofs = lcnt + KROWS;                // 257
            int* sc   = lofs + KROWS + 1;            // 256
            int bk = q - NBU;
            int start = bk * KCAP;
            int n = __hip_atomic_load(&kgCur[bk], __ATOMIC_RELAXED,
                                      __HIP_MEMORY_SCOPE_AGENT);
            if (n > KCAP) n = KCAP;

            if (t < KROWS) lcnt[t] = 0;
            __syncthreads();
            for (int i = t; i < n; i += 1024)
                atomicAdd(&lcnt[(kgPay[start + i] >> 21) & (KROWS - 1)], 1);
            __syncthreads();
            if (t < KROWS) sc[t] = lcnt[t];
            __syncthreads();
            for (int off = 1; off < KROWS; off <<= 1) {
                int v = (t < KROWS && t >= off) ? sc[t - off] : 0;
                __syncthreads();
                if (t < KROWS) sc[t] += v;
                __syncthreads();
            }
            if (t < KROWS) { int e = sc[t] - lcnt[t]; lofs[t] = e; lcnt[t] = e; }
            if (t == 0) lofs[KROWS] = n;
            __syncthreads();
            for (int i = t; i < n; i += 1024) {
                int v = kgPay[start + i];
                int p = atomicAdd(&lcnt[(v >> 21) & (KROWS - 1)], 1);
                spay[p] = v;
            }
            __syncthreads();

            int rowbase = bk * KROWS;
            for (int rr = 0; rr < KROWS / 16; ++rr) {
                int r = wv * (KROWS / 16) + rr;
                int gr = rowbase + r;
                if (gr >= N_ENTITIES) break;         // wave-uniform; last bucket only
                int s0 = lofs[r], e0 = lofs[r + 1];
                int cnt = e0 - s0;
                float acc = 0.f;
                int i = s0;
                for (; i + 7 < e0; i += 8) {
                    float a0 = 0.f, a1 = 0.f;
#pragma unroll
                    for (int u = 0; u < 8; u += 2) {
                        int va = spay[i + u], vb = spay[i + u + 1];
                        a0 += entity_emb[(va & 0x1FFFF) * EMB + d] * weight[((va >> 17) & 15) * EMB + d];
                        a1 += entity_emb[(vb & 0x1FFFF) * EMB + d] * weight[((vb >> 17) & 15) * EMB + d];
                    }
                    acc += a0 + a1;
                }
                for (; i < e0; ++i) {
                    int v = spay[i];
                    acc += entity_emb[(v & 0x1FFFF) * EMB + d] * weight[((v >> 17) & 15) * EMB + d];
                }
                ent_out[gr * EMB + d] = acc / fmaxf((float)cnt, 1.f);
            }
        }
    }
}

// ============================================================================
// Fallback atomic path (verified) — only if ws too small
// ============================================================================
__global__ void kg_scatter(const int* __restrict__ head, const int* __restrict__ tail,
                           const int* __restrict__ etype,
                           const float* __restrict__ entity_emb,
                           const float* __restrict__ weight,
                           float* __restrict__ sums, float* __restrict__ cnt) {
    int gid = blockIdx.x * blockDim.x + threadIdx.x;
    int e = gid >> 6, d = threadIdx.x & 63;
    if (e >= N_EDGES) return;
    int h = head[e], t = tail[e], w = etype[e] - 1;
    float v = entity_emb[t * EMB + d] * weight[w * EMB + d];
    unsafeAtomicAdd(&sums[h * EMB + d], v);
    if (d == 0) unsafeAtomicAdd(&cnt[h], 1.0f);
}

__global__ void user_scatter(const int* __restrict__ rows, const int* __restrict__ cols,
                             const float* __restrict__ vals,
                             const float* __restrict__ entity_emb,
                             float* __restrict__ user_sums) {
    int gid = blockIdx.x * blockDim.x + threadIdx.x;
    int e = gid >> 6, d = threadIdx.x & 63;
    if (e >= NNZ) return;
    float v = vals[e] * entity_emb[cols[e] * EMB + d];
    unsafeAtomicAdd(&user_sums[rows[e] * EMB + d], v);
}

__global__ void entity_div(float* __restrict__ ent, const float* __restrict__ cnt) {
    int gid = blockIdx.x * blockDim.x + threadIdx.x;
    if (gid >= N_ENTITIES * EMB) return;
    float c = cnt[gid >> 6];
    ent[gid] = ent[gid] / fmaxf(c, 1.0f);
}

__global__ void user_finalize(const float* __restrict__ user_emb,
                              const float* __restrict__ P,
                              const float* __restrict__ c,
                              const float* __restrict__ W_user_att,
                              const float* __restrict__ b_user_att,
                              const float* __restrict__ latent_new,
                              float* __restrict__ user_out) {
    int gid = blockIdx.x * blockDim.x + threadIdx.x;
    int u = gid >> 6, lane = threadIdx.x & 63;
    if (u >= N_USERS) return;
    float ue = user_emb[u * 64 + lane];
    float s[8];
#pragma unroll
    for (int f = 0; f < 8; ++f) s[f] = ue * P[lane * 8 + f];
#pragma unroll
    for (int off = 32; off; off >>= 1)
#pragma unroll
        for (int f = 0; f < 8; ++f) s[f] += __shfl_xor(s[f], off, 64);
#pragma unroll
    for (int f = 0; f < 8; ++f) s[f] += c[f];
    float att[8], mx = -1e30f;
#pragma unroll
    for (int k = 0; k < 8; ++k) {
        float a = b_user_att[k];
#pragma unroll
        for (int j = 0; j < 8; ++j) a += s[j] * W_user_att[k * 8 + j];
        a = a > 0.f ? a : SLOPE * a;
        att[k] = a;
        mx = fmaxf(mx, a);
    }
    float sum = 0.f;
#pragma unroll
    for (int k = 0; k < 8; ++k) { att[k] = expf(att[k] - mx); sum += att[k]; }
    float inv = 1.f / sum, g = 0.f;
#pragma unroll
    for (int f = 0; f < 8; ++f) g += att[f] * inv * latent_new[f * 64 + lane];
    float ua = user_out[u * 64 + lane];
    user_out[u * 64 + lane] = ua * (1.f + g);
}

extern "C" void kernel_launch(void* const* d_in, const int* in_sizes, int n_in,
                              void* d_out, int out_size, void* d_ws, size_t ws_size,
                              hipStream_t stream) {
    const float* entity_emb   = (const float*)d_in[0];
    const float* user_emb     = (const float*)d_in[1];
    const float* latent_emb   = (const float*)d_in[2];
    const int*   edge_index   = (const int*)d_in[3];
    const int*   edge_type    = (const int*)d_in[4];
    const int*   irows        = (const int*)d_in[5];
    const int*   icols        = (const int*)d_in[6];
    const float* ivals        = (const float*)d_in[7];
    const float* weight       = (const float*)d_in[8];
    const float* W_user_att   = (const float*)d_in[10];
    const float* b_user_att   = (const float*)d_in[11];
    const float* W_weight_att = (const float*)d_in[12];
    const float* b_weight_att = (const float*)d_in[13];
    const float* W1           = (const float*)d_in[14];
    const float* b1           = (const float*)d_in[15];
    const float* W2           = (const float*)d_in[16];
    const float* b2           = (const float*)d_in[17];

    float* out      = (float*)d_out;
    float* ent_out  = out;
    float* user_out = out + (size_t)N_ENTITIES * EMB;
    float* lat_out  = user_out + (size_t)N_USERS * EMB;

    const int* head = edge_index;
    const int* tail = edge_index + N_EDGES;

    // ---- workspace layout ----
    int* ws_i = (int*)d_ws;
    int*   ctrs   = ws_i;                         // 4
    int*   kgCur  = ctrs + 4;                     // 391
    int*   uCur   = kgCur + NBK;                  // 391 (total 786, even)
    int*   kgPay  = uCur + NBU;                   // NBK*KCAP ints
    int2*  uPay   = (int2*)(kgPay + NBK * KCAP);  // NBU*UCAP int2 (8 B aligned)
    float* Pbuf   = (float*)(uPay + NBU * UCAP);  // 512
    float* cbuf   = Pbuf + 64 * 8;                // 8
    size_t need = (size_t)(4 + NBK + NBU + (size_t)NBK * KCAP +
                           2 * (size_t)NBU * UCAP + 512 + 8) * 4;

    if (ws_size >= need) {
        // zero counters + cursors in one memset (contiguous, 3144 B)
        hipMemsetAsync(ctrs, 0, (size_t)(4 + NBK + NBU) * sizeof(int), stream);
        fused_all<<<ACCBLK, 1024, 0, stream>>>(head, tail, edge_type,
                                               irows, icols, ivals,
                                               ctrs, kgCur, uCur, kgPay, uPay,
                                               latent_emb, weight,
                                               W_weight_att, b_weight_att,
                                               W1, b1, W2, b2,
                                               entity_emb, user_emb,
                                               W_user_att, b_user_att,
                                               Pbuf, cbuf, lat_out,
                                               ent_out, user_out);
    } else {
        // ---------- fallback atomic path ----------
        float* cnt   = (float*)d_ws;
        float* Pbuf3 = cnt + N_ENTITIES;
        float* cbuf3 = Pbuf3 + 64 * 8;
        hipMemsetAsync(ent_out, 0,
                       (size_t)(N_ENTITIES + N_USERS) * EMB * sizeof(float), stream);
        hipMemsetAsync(cnt, 0, N_ENTITIES * sizeof(float), stream);
        int blocks_edges = (N_EDGES * 64) / 256;
        kg_scatter<<<blocks_edges, 256, 0, stream>>>(head, tail, edge_type, entity_emb,
                                                     weight, ent_out, cnt);
        user_scatter<<<blocks_edges, 256, 0, stream>>>(irows, icols, ivals, entity_emb,
                                                       user_out);
        small_dense<<<1, 64, 0, stream>>>(latent_emb, weight, W_weight_att,
                                          b_weight_att, W1, b1, W2, b2,
                                          Pbuf3, cbuf3, lat_out);
        user_finalize<<<(N_USERS * 64) / 256, 256, 0, stream>>>(user_emb, Pbuf3, cbuf3,
                                                                W_user_att, b_user_att,
                                                                lat_out, user_out);
        entity_div<<<(N_ENTITIES * EMB) / 256, 256, 0, stream>>>(ent_out, cnt);
    }
}

// Round 12
// 377.118 us; speedup vs baseline: 2.1727x; 2.1727x over previous
//
#include <hip/hip_runtime.h>

#define N_USERS    50000
#define N_ENTITIES 100000
#define EMB        64
#define N_EDGES    2000000
#define NNZ        2000000
#define SLOPE      0.2f

// ---- bucket geometry (r6-verified static-region tier) ----------------------
#define KROWS   256                 // entity rows per kg bucket
#define KSHIFT  8
#define NBK     391                 // ceil(100000/256)
#define UROWS   128                 // user rows per bucket
#define USHIFT  7
#define NBU     391                 // ceil(50000/128)
#define CAPK    8192                // LDS payload capacity (kg, 4 B)
#define CAPU    7680                // LDS payload capacity (user, 8 B)
#define KCAP    5632                // static region: mean 5115 + 7.2 sigma
#define UCAP    5632
#define CHK_K   8192                // kg edges per scatter block
#define PB_K    ((N_EDGES + CHK_K - 1) / CHK_K)      // 245
#define CHK_U   4096                // user nnz per scatter block
#define PB_U    ((NNZ + CHK_U - 1) / CHK_U)          // 489
#define NQ      (NBK + NBU)         // 782 buckets in steal queue
#define ACCBLK  512                 // persistent acc blocks (2/CU thread-cap)

// ============================================================================
// init: bucket cursors to region bases + steal counter
// ============================================================================
__global__ void init_cur(int* __restrict__ kgCur, int* __restrict__ uCur,
                         int* __restrict__ qCtr) {
    int t = blockIdx.x * blockDim.x + threadIdx.x;
    if (t < NBK) kgCur[t] = t * KCAP;
    if (t < NBU) uCur[t]  = t * UCAP;
    if (t == 0) qCtr[0] = 0;
}

// ============================================================================
// Small dense math: latent_new, P = W1^T*lat1^T, c = b1*lat1^T.
// Fused into scatter_both's last block.
// ============================================================================
__device__ void small_dense_body(int l,
                                 const float* __restrict__ latent_emb,
                                 const float* __restrict__ weight,
                                 const float* __restrict__ W_weight_att,
                                 const float* __restrict__ b_weight_att,
                                 const float* __restrict__ W1,
                                 const float* __restrict__ b1,
                                 const float* __restrict__ W2,
                                 const float* __restrict__ b2,
                                 float* __restrict__ P_out,
                                 float* __restrict__ c_out,
                                 float* __restrict__ latent_new_out) {
    __shared__ float lat1[8 * 64];
    __shared__ float lat2[8 * 64];
    __shared__ float wl2[16 * 64];
    __shared__ float srp[8 * 16];
    __shared__ float soft[8 * 16];

    if (l < 64) {
        for (int f = 0; f < 8; ++f) {
            float a1 = b1[l], a2 = b2[l];
            for (int k = 0; k < 64; ++k) {
                float le = latent_emb[f * 64 + k];
                a1 += le * W1[l * 64 + k];
                a2 += le * W2[l * 64 + k];
            }
            lat1[f * 64 + l] = a1;
            lat2[f * 64 + l] = a2;
        }
        for (int r = 0; r < 16; ++r) {
            float a = b2[l];
            for (int k = 0; k < 64; ++k) a += weight[r * 64 + k] * W2[l * 64 + k];
            wl2[r * 64 + l] = a;
        }
    }
    __syncthreads();

    if (l < 64) {
        for (int f = 0; f < 8; ++f) {
            float p = 0.f;
            for (int d = 0; d < 64; ++d) p += W1[d * 64 + l] * lat1[f * 64 + d];
            P_out[l * 8 + f] = p;
        }
        if (l < 8) {
            float cc = 0.f;
            for (int d = 0; d < 64; ++d) cc += b1[d] * lat1[l * 64 + d];
            c_out[l] = cc;
        }
        for (int idx = l; idx < 128; idx += 64) {
            int f = idx >> 4, r = idx & 15;
            float a = 0.f;
            for (int d = 0; d < 64; ++d) a += lat2[f * 64 + d] * wl2[r * 64 + d];
            srp[idx] = a;
        }
    }
    __syncthreads();

    if (l < 8) {
        int f = l;
        float att[16];
        float mx = -1e30f;
        for (int k = 0; k < 16; ++k) {
            float a = b_weight_att[k];
            for (int j = 0; j < 16; ++j) a += srp[f * 16 + j] * W_weight_att[k * 16 + j];
            a = a > 0.f ? a : SLOPE * a;
            att[k] = a;
            mx = fmaxf(mx, a);
        }
        float s = 0.f;
        for (int k = 0; k < 16; ++k) { att[k] = expf(att[k] - mx); s += att[k]; }
        float inv = 1.f / s;
        for (int k = 0; k < 16; ++k) soft[f * 16 + k] = att[k] * inv;
    }
    __syncthreads();

    if (l < 64) {
        for (int f = 0; f < 8; ++f) {
            float a = 0.f;
            for (int r = 0; r < 16; ++r) a += soft[f * 16 + r] * weight[r * 64 + l];
            latent_new_out[f * 64 + l] = a;
        }
    }
}

__global__ void small_dense(const float* __restrict__ latent_emb,
                            const float* __restrict__ weight,
                            const float* __restrict__ W_weight_att,
                            const float* __restrict__ b_weight_att,
                            const float* __restrict__ W1,
                            const float* __restrict__ b1,
                            const float* __restrict__ W2,
                            const float* __restrict__ b2,
                            float* __restrict__ P_out,
                            float* __restrict__ c_out,
                            float* __restrict__ latent_new_out) {
    small_dense_body(threadIdx.x, latent_emb, weight, W_weight_att, b_weight_att,
                     W1, b1, W2, b2, P_out, c_out, latent_new_out);
}

// ============================================================================
// Partition (r6-verified): register-stage keys -> LDS histogram -> reserve
// region space via atomicAdd on cursors (pre-set to region bases) -> block
// scan -> counting-sort payload into LDS -> coalesced linear output sweep.
// blocks [0,PB_K) = kg; [PB_K,PB_K+PB_U) = user; last block = small dense.
// kg payload: tail(0..16) | type-1 (17..20) | rowlow (21..28)
// user payload: int2 { col(0..16) | rowlow(17..23), val_bits }
// ============================================================================
__global__ __launch_bounds__(512) void scatter_both(const int* __restrict__ head,
                                                    const int* __restrict__ tail,
                                                    const int* __restrict__ etype,
                                                    int* __restrict__ kgCur,
                                                    int* __restrict__ kgPay,
                                                    const int* __restrict__ urows,
                                                    const int* __restrict__ ucols,
                                                    const float* __restrict__ uvals,
                                                    int* __restrict__ uCur,
                                                    int2* __restrict__ uPay,
                                                    const float* __restrict__ latent_emb,
                                                    const float* __restrict__ weight,
                                                    const float* __restrict__ W_weight_att,
                                                    const float* __restrict__ b_weight_att,
                                                    const float* __restrict__ W1,
                                                    const float* __restrict__ b1,
                                                    const float* __restrict__ W2,
                                                    const float* __restrict__ b2,
                                                    float* __restrict__ Pbuf,
                                                    float* __restrict__ cbuf,
                                                    float* __restrict__ lat_out) {
    if (blockIdx.x == PB_K + PB_U) {
        small_dense_body(threadIdx.x, latent_emb, weight, W_weight_att,
                         b_weight_att, W1, b1, W2, b2, Pbuf, cbuf, lat_out);
        return;
    }

    __shared__ long long sp8[4096];      // 32 KB payload (int[8192] | int2[4096])
    __shared__ int lh[NBK];              // hist -> placement cursor
    __shared__ int lb[NBK];              // per-bucket global base for this block
    __shared__ int lofs[NBK + 1];        // local exclusive offsets
    __shared__ int sc[512];              // block scan temp
    int tid = threadIdx.x;
    bool isKg = blockIdx.x < PB_K;

    for (int t = tid; t < NBK; t += 512) lh[t] = 0;
    __syncthreads();

    if (isKg) {
        int base = blockIdx.x * CHK_K;
        int n = N_EDGES - base; if (n > CHK_K) n = CHK_K;
        int* spk = (int*)sp8;

        int kreg[CHK_K / 512];           // 16 staged keys
#pragma unroll
        for (int j = 0; j < CHK_K / 512; ++j) {
            int o = j * 512 + tid;
            int h = (o < n) ? head[base + o] : -1;
            kreg[j] = h;
            if (h >= 0) atomicAdd(&lh[h >> KSHIFT], 1);
        }
        __syncthreads();
        for (int t = tid; t < NBK; t += 512)
            lb[t] = lh[t] ? atomicAdd(&kgCur[t], lh[t]) : 0;
        int v = (tid < NBK) ? lh[tid] : 0;
        sc[tid] = v;
        __syncthreads();
        for (int off = 1; off < 512; off <<= 1) {
            int t = (tid >= off) ? sc[tid - off] : 0;
            __syncthreads();
            sc[tid] += t;
            __syncthreads();
        }
        if (tid < NBK) { int e = sc[tid] - v; lofs[tid] = e; lh[tid] = e; }
        if (tid == NBK - 1) lofs[NBK] = sc[tid];
        __syncthreads();
#pragma unroll
        for (int j = 0; j < CHK_K / 512; ++j) {
            int h = kreg[j];
            if (h >= 0) {
                int i = base + j * 512 + tid;
                int p = atomicAdd(&lh[h >> KSHIFT], 1);
                spk[p] = tail[i] | ((etype[i] - 1) << 17) | ((h & (KROWS - 1)) << 21);
            }
        }
        __syncthreads();
        for (int i = tid; i < n; i += 512) {
            int lo = 0, hi = NBK;        // invariant: lofs[lo] <= i < lofs[hi]
            while (hi - lo > 1) {
                int mid = (lo + hi) >> 1;
                if (lofs[mid] <= i) lo = mid; else hi = mid;
            }
            kgPay[lb[lo] + (i - lofs[lo])] = spk[i];
        }
    } else {
        int base = (blockIdx.x - PB_K) * CHK_U;
        int n = NNZ - base; if (n > CHK_U) n = CHK_U;
        int2* spu = (int2*)sp8;

        int kreg[CHK_U / 512];           // 8 staged keys
#pragma unroll
        for (int j = 0; j < CHK_U / 512; ++j) {
            int o = j * 512 + tid;
            int r = (o < n) ? urows[base + o] : -1;
            kreg[j] = r;
            if (r >= 0) atomicAdd(&lh[r >> USHIFT], 1);
        }
        __syncthreads();
        for (int t = tid; t < NBU; t += 512)
            lb[t] = lh[t] ? atomicAdd(&uCur[t], lh[t]) : 0;
        int v = (tid < NBU) ? lh[tid] : 0;
        sc[tid] = v;
        __syncthreads();
        for (int off = 1; off < 512; off <<= 1) {
            int t = (tid >= off) ? sc[tid - off] : 0;
            __syncthreads();
            sc[tid] += t;
            __syncthreads();
        }
        if (tid < NBU) { int e = sc[tid] - v; lofs[tid] = e; lh[tid] = e; }
        if (tid == NBU - 1) lofs[NBU] = sc[tid];
        __syncthreads();
#pragma unroll
        for (int j = 0; j < CHK_U / 512; ++j) {
            int r = kreg[j];
            if (r >= 0) {
                int i = base + j * 512 + tid;
                int p = atomicAdd(&lh[r >> USHIFT], 1);
                spu[p] = make_int2(ucols[i] | ((r & (UROWS - 1)) << 17),
                                   __float_as_int(uvals[i]));
            }
        }
        __syncthreads();
        for (int i = tid; i < n; i += 512) {
            int lo = 0, hi = NBU;
            while (hi - lo > 1) {
                int mid = (lo + hi) >> 1;
                if (lofs[mid] <= i) lo = mid; else hi = mid;
            }
            uPay[lb[lo] + (i - lofs[lo])] = spu[i];
        }
    }
}

// ============================================================================
// Persistent work-stealing accumulate — r6-verified scalar body.
// Per bucket: in-LDS counting sort to exact row, per-wave register
// accumulation, mean / attention-gating fused.
// ============================================================================
__global__ __launch_bounds__(1024, 8) void acc_both(
        const int* __restrict__ kgPay, const int* __restrict__ kgCur,
        const int2* __restrict__ uPay, const int* __restrict__ uCur,
        const float* __restrict__ entity_emb,
        const float* __restrict__ weight,
        const float* __restrict__ user_emb,
        const float* __restrict__ P,
        const float* __restrict__ cvec,
        const float* __restrict__ W_user_att,
        const float* __restrict__ b_user_att,
        const float* __restrict__ latent_new,
        int* __restrict__ qCtr,
        float* __restrict__ ent_out,
        float* __restrict__ user_out) {
    __shared__ long long smem8[7873];   // 62984 B union
    __shared__ int sbk;
    int t = threadIdx.x, d = t & 63, wv = t >> 6;    // wv 0..15

    for (;;) {
        __syncthreads();                 // previous bucket's LDS reads done
        if (t == 0) sbk = atomicAdd(qCtr, 1);
        __syncthreads();
        int q = sbk;
        if (q >= NQ) return;             // uniform exit

        if (q < NBU) {
            // ---------------- USER bucket ----------------
            int2* spay = (int2*)smem8;               // CAPU int2
            int* lcnt = (int*)(spay + CAPU);         // 128
            int* lofs = lcnt + UROWS;                // 129
            int* sc   = lofs + UROWS + 1;            // 128
            int bk = q;
            int start = bk * UCAP, end = uCur[bk];
            int n = end - start; if (n > CAPU) n = CAPU;

            if (t < UROWS) lcnt[t] = 0;
            __syncthreads();
            for (int i = t; i < n; i += 1024)
                atomicAdd(&lcnt[(uPay[start + i].x >> 17) & (UROWS - 1)], 1);
            __syncthreads();
            if (t < UROWS) sc[t] = lcnt[t];
            __syncthreads();
            for (int off = 1; off < UROWS; off <<= 1) {
                int v = (t < UROWS && t >= off) ? sc[t - off] : 0;
                __syncthreads();
                if (t < UROWS) sc[t] += v;
                __syncthreads();
            }
            if (t < UROWS) { int e = sc[t] - lcnt[t]; lofs[t] = e; lcnt[t] = e; }
            if (t == 0) lofs[UROWS] = n;
            __syncthreads();
            for (int i = t; i < n; i += 1024) {
                int2 v = uPay[start + i];
                int p = atomicAdd(&lcnt[(v.x >> 17) & (UROWS - 1)], 1);
                spay[p] = v;
            }
            __syncthreads();

            int rowbase = bk * UROWS;
            for (int rr = 0; rr < UROWS / 16; ++rr) {
                int r = wv * (UROWS / 16) + rr;
                int gr = rowbase + r;
                if (gr >= N_USERS) break;             // wave-uniform; last bucket only
                int s0 = lofs[r], e0 = lofs[r + 1];
                float acc = 0.f;
                int i = s0;
                for (; i + 7 < e0; i += 8) {
                    float a0 = 0.f, a1 = 0.f;
#pragma unroll
                    for (int u = 0; u < 8; u += 2) {
                        int2 va = spay[i + u], vb = spay[i + u + 1];
                        a0 += __int_as_float(va.y) * entity_emb[(va.x & 0x1FFFF) * EMB + d];
                        a1 += __int_as_float(vb.y) * entity_emb[(vb.x & 0x1FFFF) * EMB + d];
                    }
                    acc += a0 + a1;
                }
                for (; i < e0; ++i) {
                    int2 v = spay[i];
                    acc += __int_as_float(v.y) * entity_emb[(v.x & 0x1FFFF) * EMB + d];
                }
                for (int j = start + CAPU; j < end; ++j) {   // overflow (never taken)
                    int2 v = uPay[j];
                    if (((v.x >> 17) & (UROWS - 1)) == r)
                        acc += __int_as_float(v.y) * entity_emb[(v.x & 0x1FFFF) * EMB + d];
                }

                // fused attention gating epilogue for this row
                float ue = user_emb[gr * EMB + d];
                float s[8];
#pragma unroll
                for (int f = 0; f < 8; ++f) s[f] = ue * P[d * 8 + f];
#pragma unroll
                for (int off = 32; off; off >>= 1) {
#pragma unroll
                    for (int f = 0; f < 8; ++f) s[f] += __shfl_xor(s[f], off, 64);
                }
#pragma unroll
                for (int f = 0; f < 8; ++f) s[f] += cvec[f];
                float att[8];
                float mx = -1e30f;
#pragma unroll
                for (int k = 0; k < 8; ++k) {
                    float a = b_user_att[k];
#pragma unroll
                    for (int j = 0; j < 8; ++j) a += s[j] * W_user_att[k * 8 + j];
                    a = a > 0.f ? a : SLOPE * a;
                    att[k] = a;
                    mx = fmaxf(mx, a);
                }
                float sum = 0.f;
#pragma unroll
                for (int k = 0; k < 8; ++k) { att[k] = __expf(att[k] - mx); sum += att[k]; }
                float inv = 1.f / sum;
                float g = 0.f;
#pragma unroll
                for (int f = 0; f < 8; ++f) g += att[f] * inv * latent_new[f * EMB + d];
                user_out[gr * EMB + d] = acc * (1.f + g);
            }
        } else {
            // ---------------- KG bucket ----------------
            int* spay = (int*)smem8;                 // CAPK ints
            int* lcnt = spay + CAPK;                 // 256
            int* lofs = lcnt + KROWS;                // 257
            int* sc   = lofs + KROWS + 1;            // 256
            int bk = q - NBU;
            int start = bk * KCAP, end = kgCur[bk];
            int n = end - start; if (n > CAPK) n = CAPK;

            if (t < KROWS) lcnt[t] = 0;
            __syncthreads();
            for (int i = t; i < n; i += 1024)
                atomicAdd(&lcnt[(kgPay[start + i] >> 21) & (KROWS - 1)], 1);
            __syncthreads();
            if (t < KROWS) sc[t] = lcnt[t];
            __syncthreads();
            for (int off = 1; off < KROWS; off <<= 1) {
                int v = (t < KROWS && t >= off) ? sc[t - off] : 0;
                __syncthreads();
                if (t < KROWS) sc[t] += v;
                __syncthreads();
            }
            if (t < KROWS) { int e = sc[t] - lcnt[t]; lofs[t] = e; lcnt[t] = e; }
            if (t == 0) lofs[KROWS] = n;
            __syncthreads();
            for (int i = t; i < n; i += 1024) {
                int v = kgPay[start + i];
                int p = atomicAdd(&lcnt[(v >> 21) & (KROWS - 1)], 1);
                spay[p] = v;
            }
            __syncthreads();

            int rowbase = bk * KROWS;
            for (int rr = 0; rr < KROWS / 16; ++rr) {
                int r = wv * (KROWS / 16) + rr;
                int gr = rowbase + r;
                if (gr >= N_ENTITIES) break;          // wave-uniform; last bucket only
                int s0 = lofs[r], e0 = lofs[r + 1];
                int cnt = e0 - s0;
                float acc = 0.f;
                int i = s0;
                for (; i + 7 < e0; i += 8) {
                    float a0 = 0.f, a1 = 0.f;
#pragma unroll
                    for (int u = 0; u < 8; u += 2) {
                        int va = spay[i + u], vb = spay[i + u + 1];
                        a0 += entity_emb[(va & 0x1FFFF) * EMB + d] * weight[((va >> 17) & 15) * EMB + d];
                        a1 += entity_emb[(vb & 0x1FFFF) * EMB + d] * weight[((vb >> 17) & 15) * EMB + d];
                    }
                    acc += a0 + a1;
                }
                for (; i < e0; ++i) {
                    int v = spay[i];
                    acc += entity_emb[(v & 0x1FFFF) * EMB + d] * weight[((v >> 17) & 15) * EMB + d];
                }
                // overflow tail (statistically never taken)
                for (int j = start + CAPK; j < end; ++j) {
                    int v = kgPay[j];
                    if (((v >> 21) & (KROWS - 1)) == r) {
                        acc += entity_emb[(v & 0x1FFFF) * EMB + d] * weight[((v >> 17) & 15) * EMB + d];
                        ++cnt;
                    }
                }
                ent_out[gr * EMB + d] = acc / fmaxf((float)cnt, 1.f);
            }
        }
    }
}

// ============================================================================
// Fallback atomic path (verified) — only if ws too small
// ============================================================================
__global__ void kg_scatter(const int* __restrict__ head, const int* __restrict__ tail,
                           const int* __restrict__ etype,
                           const float* __restrict__ entity_emb,
                           const float* __restrict__ weight,
                           float* __restrict__ sums, float* __restrict__ cnt) {
    int gid = blockIdx.x * blockDim.x + threadIdx.x;
    int e = gid >> 6, d = threadIdx.x & 63;
    if (e >= N_EDGES) return;
    int h = head[e], t = tail[e], w = etype[e] - 1;
    float v = entity_emb[t * EMB + d] * weight[w * EMB + d];
    unsafeAtomicAdd(&sums[h * EMB + d], v);
    if (d == 0) unsafeAtomicAdd(&cnt[h], 1.0f);
}

__global__ void user_scatter(const int* __restrict__ rows, const int* __restrict__ cols,
                             const float* __restrict__ vals,
                             const float* __restrict__ entity_emb,
                             float* __restrict__ user_sums) {
    int gid = blockIdx.x * blockDim.x + threadIdx.x;
    int e = gid >> 6, d = threadIdx.x & 63;
    if (e >= NNZ) return;
    float v = vals[e] * entity_emb[cols[e] * EMB + d];
    unsafeAtomicAdd(&user_sums[rows[e] * EMB + d], v);
}

__global__ void entity_div(float* __restrict__ ent, const float* __restrict__ cnt) {
    int gid = blockIdx.x * blockDim.x + threadIdx.x;
    if (gid >= N_ENTITIES * EMB) return;
    float c = cnt[gid >> 6];
    ent[gid] = ent[gid] / fmaxf(c, 1.0f);
}

__global__ void user_finalize(const float* __restrict__ user_emb,
                              const float* __restrict__ P,
                              const float* __restrict__ c,
                              const float* __restrict__ W_user_att,
                              const float* __restrict__ b_user_att,
                              const float* __restrict__ latent_new,
                              float* __restrict__ user_out) {
    int gid = blockIdx.x * blockDim.x + threadIdx.x;
    int u = gid >> 6, lane = threadIdx.x & 63;
    if (u >= N_USERS) return;
    float ue = user_emb[u * 64 + lane];
    float s[8];
#pragma unroll
    for (int f = 0; f < 8; ++f) s[f] = ue * P[lane * 8 + f];
#pragma unroll
    for (int off = 32; off; off >>= 1)
#pragma unroll
        for (int f = 0; f < 8; ++f) s[f] += __shfl_xor(s[f], off, 64);
#pragma unroll
    for (int f = 0; f < 8; ++f) s[f] += c[f];
    float att[8], mx = -1e30f;
#pragma unroll
    for (int k = 0; k < 8; ++k) {
        float a = b_user_att[k];
#pragma unroll
        for (int j = 0; j < 8; ++j) a += s[j] * W_user_att[k * 8 + j];
        a = a > 0.f ? a : SLOPE * a;
        att[k] = a;
        mx = fmaxf(mx, a);
    }
    float sum = 0.f;
#pragma unroll
    for (int k = 0; k < 8; ++k) { att[k] = expf(att[k] - mx); sum += att[k]; }
    float inv = 1.f / sum, g = 0.f;
#pragma unroll
    for (int f = 0; f < 8; ++f) g += att[f] * inv * latent_new[f * 64 + lane];
    float ua = user_out[u * 64 + lane];
    user_out[u * 64 + lane] = ua * (1.f + g);
}

extern "C" void kernel_launch(void* const* d_in, const int* in_sizes, int n_in,
                              void* d_out, int out_size, void* d_ws, size_t ws_size,
                              hipStream_t stream) {
    const float* entity_emb   = (const float*)d_in[0];
    const float* user_emb     = (const float*)d_in[1];
    const float* latent_emb   = (const float*)d_in[2];
    const int*   edge_index   = (const int*)d_in[3];
    const int*   edge_type    = (const int*)d_in[4];
    const int*   irows        = (const int*)d_in[5];
    const int*   icols        = (const int*)d_in[6];
    const float* ivals        = (const float*)d_in[7];
    const float* weight       = (const float*)d_in[8];
    const float* W_user_att   = (const float*)d_in[10];
    const float* b_user_att   = (const float*)d_in[11];
    const float* W_weight_att = (const float*)d_in[12];
    const float* b_weight_att = (const float*)d_in[13];
    const float* W1           = (const float*)d_in[14];
    const float* b1           = (const float*)d_in[15];
    const float* W2           = (const float*)d_in[16];
    const float* b2           = (const float*)d_in[17];

    float* out      = (float*)d_out;
    float* ent_out  = out;
    float* user_out = out + (size_t)N_ENTITIES * EMB;
    float* lat_out  = user_out + (size_t)N_USERS * EMB;

    const int* head = edge_index;
    const int* tail = edge_index + N_EDGES;

    // ---- static-tier workspace layout ----
    int* ws_i = (int*)d_ws;
    int*   qCtr   = ws_i;                         // 2
    int*   kgCur  = qCtr + 2;                     // 391
    int*   uCur   = kgCur + NBK;                  // 391 (kgPay idx 784, even)
    int*   kgPay  = uCur + NBU;                   // NBK*KCAP ints
    int2*  uPay   = (int2*)(kgPay + NBK * KCAP);  // NBU*UCAP int2 (8 B aligned)
    float* Pbuf   = (float*)(uPay + NBU * UCAP);  // 512
    float* cbuf   = Pbuf + 64 * 8;                // 8
    size_t need_static = (size_t)(2 + NBK + NBU + (size_t)NBK * KCAP +
                                  2 * (size_t)NBU * UCAP + 512 + 8) * 4;

    if (ws_size >= need_static) {
        init_cur<<<2, 256, 0, stream>>>(kgCur, uCur, qCtr);
        scatter_both<<<PB_K + PB_U + 1, 512, 0, stream>>>(head, tail, edge_type,
                                                          kgCur, kgPay,
                                                          irows, icols, ivals,
                                                          uCur, uPay,
                                                          latent_emb, weight,
                                                          W_weight_att, b_weight_att,
                                                          W1, b1, W2, b2,
                                                          Pbuf, cbuf, lat_out);
        acc_both<<<ACCBLK, 1024, 0, stream>>>(kgPay, kgCur, uPay, uCur,
                                              entity_emb, weight, user_emb,
                                              Pbuf, cbuf, W_user_att, b_user_att,
                                              lat_out, qCtr, ent_out, user_out);
    } else {
        // ---------- fallback atomic path ----------
        float* cnt   = (float*)d_ws;
        float* Pbuf3 = cnt + N_ENTITIES;
        float* cbuf3 = Pbuf3 + 64 * 8;
        hipMemsetAsync(ent_out, 0,
                       (size_t)(N_ENTITIES + N_USERS) * EMB * sizeof(float), stream);
        hipMemsetAsync(cnt, 0, N_ENTITIES * sizeof(float), stream);
        int blocks_edges = (N_EDGES * 64) / 256;
        kg_scatter<<<blocks_edges, 256, 0, stream>>>(head, tail, edge_type, entity_emb,
                                                     weight, ent_out, cnt);
        user_scatter<<<blocks_edges, 256, 0, stream>>>(irows, icols, ivals, entity_emb,
                                                       user_out);
        small_dense<<<1, 64, 0, stream>>>(latent_emb, weight, W_weight_att,
                                          b_weight_att, W1, b1, W2, b2,
                                          Pbuf3, cbuf3, lat_out);
        user_finalize<<<(N_USERS * 64) / 256, 256, 0, stream>>>(user_emb, Pbuf3, cbuf3,
                                                                W_user_att, b_user_att,
                                                                lat_out, user_out);
        entity_div<<<(N_ENTITIES * EMB) / 256, 256, 0, stream>>>(ent_out, cnt);
    }
}